// Round 3
// baseline (748.485 us; speedup 1.0000x reference)
//
#include <hip/hip_runtime.h>
#include <hip/hip_bf16.h>
#include <stdint.h>

// Problem constants
#define S_LEN 2048
#define EMB   1024
#define NH    16
#define DH    64
#define BATCH 2

typedef short bf16x8 __attribute__((ext_vector_type(8)));
typedef float f32x4  __attribute__((ext_vector_type(4)));

__device__ __forceinline__ unsigned short f2bf(float f) {
    union { float f; unsigned int u; } v; v.f = f;
    unsigned int r = v.u + 0x7FFFu + ((v.u >> 16) & 1u);
    return (unsigned short)(r >> 16);
}

__device__ __forceinline__ bf16x8 load8f_to_bf(const float* __restrict__ p) {
    const float4* p4 = (const float4*)p;
    float4 x0 = p4[0];
    float4 x1 = p4[1];
    bf16x8 r;
    r[0] = (short)f2bf(x0.x); r[1] = (short)f2bf(x0.y);
    r[2] = (short)f2bf(x0.z); r[3] = (short)f2bf(x0.w);
    r[4] = (short)f2bf(x1.x); r[5] = (short)f2bf(x1.y);
    r[6] = (short)f2bf(x1.z); r[7] = (short)f2bf(x1.w);
    return r;
}

// ---------------------------------------------------------------------------
// Kernel 1: fused QKV projection.  q[b,s,f] = sum_e x[b,s,e] * W[f,e]
// Output: Qb, Kb as bf16 [bh][s][64]; V transposed Vt as bf16 [bh][64][s].
// Block = 256 thr (4 waves, 2x2), tile 128x128 over (M=4096, N=3072 concat).
// ---------------------------------------------------------------------------
__global__ __launch_bounds__(256) void proj_kernel(
    const float* __restrict__ x,
    const float* __restrict__ Wq, const float* __restrict__ Wk,
    const float* __restrict__ Wv,
    unsigned short* __restrict__ Qb, unsigned short* __restrict__ Kb,
    unsigned short* __restrict__ Vt)
{
    const int tid  = threadIdx.x;
    const int lane = tid & 63;
    const int w    = tid >> 6;      // 0..3
    const int wr   = w >> 1;        // 0..1
    const int wc   = w & 1;         // 0..1
    const int m0   = blockIdx.x * 128 + wr * 64;
    const int c0   = blockIdx.y * 128 + wc * 64;   // global col in [0,3072)
    const int wsel = c0 >> 10;                      // 0=Q,1=K,2=V
    const int f0   = c0 & 1023;
    const float* __restrict__ W = (wsel == 0) ? Wq : (wsel == 1) ? Wk : Wv;

    const int lr = lane & 15;
    const int lk = (lane >> 4) * 8;

    f32x4 acc[4][4];
#pragma unroll
    for (int i = 0; i < 4; i++)
#pragma unroll
        for (int n = 0; n < 4; n++) acc[i][n] = (f32x4){0.f, 0.f, 0.f, 0.f};

    for (int k0 = 0; k0 < 1024; k0 += 32) {
        bf16x8 a[4], b[4];
#pragma unroll
        for (int i = 0; i < 4; i++)
            a[i] = load8f_to_bf(&x[(size_t)(m0 + i * 16 + lr) * 1024 + k0 + lk]);
#pragma unroll
        for (int n = 0; n < 4; n++)
            b[n] = load8f_to_bf(&W[(size_t)(f0 + n * 16 + lr) * 1024 + k0 + lk]);
#pragma unroll
        for (int i = 0; i < 4; i++)
#pragma unroll
            for (int n = 0; n < 4; n++)
                acc[i][n] = __builtin_amdgcn_mfma_f32_16x16x32_bf16(a[i], b[n], acc[i][n], 0, 0, 0);
    }

    // Epilogue: C layout col=lane&15, row=(lane>>4)*4+reg
    const int g = lane >> 4;
#pragma unroll
    for (int i = 0; i < 4; i++) {
#pragma unroll
        for (int n = 0; n < 4; n++) {
#pragma unroll
            for (int j = 0; j < 4; j++) {
                int row_m = m0 + i * 16 + g * 4 + j;   // b*S + s
                int c     = c0 + n * 16 + lr;
                int f     = c & 1023;
                int h     = f >> 6;
                int dd    = f & 63;
                int bb    = row_m >> 11;
                int s     = row_m & 2047;
                int bh    = bb * 16 + h;
                unsigned short bv = f2bf(acc[i][n][j]);
                if (wsel == 0)      Qb[((size_t)bh * 2048 + s) * 64 + dd] = bv;
                else if (wsel == 1) Kb[((size_t)bh * 2048 + s) * 64 + dd] = bv;
                else                Vt[((size_t)bh * 64 + dd) * 2048 + s] = bv;
            }
        }
    }
}

// ---------------------------------------------------------------------------
// Er f32 -> bf16
// ---------------------------------------------------------------------------
__global__ void cvt_er(const float* __restrict__ Er, unsigned short* __restrict__ Erb, int n)
{
    int i = blockIdx.x * 256 + threadIdx.x;
    if (i < n) Erb[i] = f2bf(Er[i]);
}

// ---------------------------------------------------------------------------
// Kernel 2: flash attention with relative positions.
// Grid: (32 q-tiles, 32 bh). Block = 256 thr = 4 waves, each wave owns a
// 16-row q strip, iterates 64-key causal tiles.
// score[q,k] = (q.k + q.Er[2047+k-q]) / 8
// Rel term per tile: Rt[i][wcol] = Qrow_i . Er[rbase+wcol], wcol in [0,80),
// rbase = 2047 + k0 - q0w - 15; read back at wcol = jj + 15 - i.
// OUTPUT IS FLOAT32 (reference returns jnp.float32; harness matches ref dtype).
// ---------------------------------------------------------------------------
__global__ __launch_bounds__(256) void attn_kernel(
    const unsigned short* __restrict__ Qb, const unsigned short* __restrict__ Kb,
    const unsigned short* __restrict__ Vt, const unsigned short* __restrict__ Erb,
    float* __restrict__ out)
{
    __shared__ __align__(16) float          Rt[4][16][80];
    __shared__ __align__(16) unsigned short Pl[4][16][72];

    const int tid  = threadIdx.x;
    const int lane = tid & 63;
    const int w    = tid >> 6;
    const int qt   = 31 - blockIdx.x;     // heavy tiles first
    const int bh   = blockIdx.y;
    const int q0w  = qt * 64 + w * 16;

    const int lr = lane & 15;
    const int g  = lane >> 4;
    const int lk = g * 8;

    const unsigned short* __restrict__ Qrow = Qb + (size_t)bh * 2048 * 64;
    const unsigned short* __restrict__ Krow = Kb + (size_t)bh * 2048 * 64;
    const unsigned short* __restrict__ Vrow = Vt + (size_t)bh * 64 * 2048;

    // Q fragments held in registers for the whole kernel
    bf16x8 aq[2];
    aq[0] = *(const bf16x8*)&Qrow[(size_t)(q0w + lr) * 64 + 0  + lk];
    aq[1] = *(const bf16x8*)&Qrow[(size_t)(q0w + lr) * 64 + 32 + lk];

    f32x4 o[4];
#pragma unroll
    for (int n = 0; n < 4; n++) o[n] = (f32x4){0.f, 0.f, 0.f, 0.f};
    float m[4], lsum[4];
#pragma unroll
    for (int j = 0; j < 4; j++) { m[j] = -1e30f; lsum[j] = 0.f; }

    const float SCL = 0.125f * 1.44269504089f;  // (1/sqrt(64)) * log2(e)

    for (int kt = 0; kt <= qt; kt++) {
        const int k0 = kt * 64;

        // ---- QK^T : 16x64 strip ----
        f32x4 s[4];
#pragma unroll
        for (int n = 0; n < 4; n++) s[n] = (f32x4){0.f, 0.f, 0.f, 0.f};
#pragma unroll
        for (int kk = 0; kk < 2; kk++) {
#pragma unroll
            for (int n = 0; n < 4; n++) {
                bf16x8 bk = *(const bf16x8*)&Krow[(size_t)(k0 + n * 16 + lr) * 64 + kk * 32 + lk];
                s[n] = __builtin_amdgcn_mfma_f32_16x16x32_bf16(aq[kk], bk, s[n], 0, 0, 0);
            }
        }

        // ---- Q @ Er-window^T : 16x80 strip ----
        f32x4 r[5];
#pragma unroll
        for (int n = 0; n < 5; n++) r[n] = (f32x4){0.f, 0.f, 0.f, 0.f};
        const int rbase = 2047 + k0 - q0w - 15;
#pragma unroll
        for (int kk = 0; kk < 2; kk++) {
#pragma unroll
            for (int n = 0; n < 5; n++) {
                int rr = rbase + n * 16 + lr;
                rr = rr < 0 ? 0 : (rr > 2047 ? 2047 : rr);
                bf16x8 be = *(const bf16x8*)&Erb[(size_t)rr * 64 + kk * 32 + lk];
                r[n] = __builtin_amdgcn_mfma_f32_16x16x32_bf16(aq[kk], be, r[n], 0, 0, 0);
            }
        }
        // stash Rt in LDS (cross-lane exchange: D-layout write, transposed read)
#pragma unroll
        for (int n = 0; n < 5; n++)
#pragma unroll
            for (int j = 0; j < 4; j++)
                Rt[w][g * 4 + j][n * 16 + lr] = r[n][j];

        __syncthreads();   // fence Rt writes -> cross-lane reads (and prev Pl reads -> this iter)

        // ---- combine + causal mask + online softmax ----
        float p[4][4];   // [n][j]
        float pm[4];
#pragma unroll
        for (int j = 0; j < 4; j++) pm[j] = -1e30f;
#pragma unroll
        for (int n = 0; n < 4; n++) {
#pragma unroll
            for (int j = 0; j < 4; j++) {
                int i  = g * 4 + j;
                int jj = n * 16 + lr;
                float sc = (s[n][j] + Rt[w][i][jj + 15 - i]) * SCL;
                if (k0 + jj > q0w + i) sc = -1e30f;
                p[n][j] = sc;
                pm[j]   = fmaxf(pm[j], sc);
            }
        }
#pragma unroll
        for (int j = 0; j < 4; j++) {
            float v = pm[j];
            v = fmaxf(v, __shfl_xor(v, 1));
            v = fmaxf(v, __shfl_xor(v, 2));
            v = fmaxf(v, __shfl_xor(v, 4));
            v = fmaxf(v, __shfl_xor(v, 8));
            pm[j] = v;
        }
#pragma unroll
        for (int j = 0; j < 4; j++) {
            float mn   = fmaxf(m[j], pm[j]);
            float corr = exp2f(m[j] - mn);
            m[j] = mn;
            float rs = 0.f;
#pragma unroll
            for (int n = 0; n < 4; n++) {
                float pv = exp2f(p[n][j] - mn);
                p[n][j] = pv;
                rs += pv;
            }
            rs += __shfl_xor(rs, 1);
            rs += __shfl_xor(rs, 2);
            rs += __shfl_xor(rs, 4);
            rs += __shfl_xor(rs, 8);
            lsum[j] = lsum[j] * corr + rs;
#pragma unroll
            for (int n = 0; n < 4; n++) o[n][j] *= corr;
        }

        // ---- P -> LDS (bf16) -> A-fragments ----
#pragma unroll
        for (int n = 0; n < 4; n++)
#pragma unroll
            for (int j = 0; j < 4; j++)
                Pl[w][g * 4 + j][n * 16 + lr] = f2bf(p[n][j]);

        __syncthreads();   // fence Pl writes -> cross-lane A-frag reads (and Rt reads -> next iter)

        // ---- P @ V ----
#pragma unroll
        for (int kk = 0; kk < 2; kk++) {
            bf16x8 pa = *(const bf16x8*)&Pl[w][lr][kk * 32 + lk];
#pragma unroll
            for (int n = 0; n < 4; n++) {
                bf16x8 bv = *(const bf16x8*)&Vrow[(size_t)(n * 16 + lr) * 2048 + k0 + kk * 32 + lk];
                o[n] = __builtin_amdgcn_mfma_f32_16x16x32_bf16(pa, bv, o[n], 0, 0, 0);
            }
        }
    }

    // ---- epilogue: out[b, q, h*64+dd] FLOAT32 ----
    const int bb = bh >> 4;
    const int h  = bh & 15;
#pragma unroll
    for (int n = 0; n < 4; n++) {
#pragma unroll
        for (int j = 0; j < 4; j++) {
            int row = q0w + g * 4 + j;
            int col = h * 64 + n * 16 + lr;
            out[((size_t)bb * 2048 + row) * 1024 + col] = o[n][j] / lsum[j];
        }
    }
}

// ---------------------------------------------------------------------------
extern "C" void kernel_launch(void* const* d_in, const int* in_sizes, int n_in,
                              void* d_out, int out_size, void* d_ws, size_t ws_size,
                              hipStream_t stream)
{
    const float* x  = (const float*)d_in[0];
    const float* Wq = (const float*)d_in[1];
    const float* Wk = (const float*)d_in[2];
    const float* Wv = (const float*)d_in[3];
    const float* Er = (const float*)d_in[4];
    float* out = (float*)d_out;   // f32 output (reference returns jnp.float32)

    char* ws = (char*)d_ws;
    unsigned short* Qb  = (unsigned short*)(ws);                            // 8 MB
    unsigned short* Kb  = (unsigned short*)(ws + (size_t)8  * 1024 * 1024); // 8 MB
    unsigned short* Vt  = (unsigned short*)(ws + (size_t)16 * 1024 * 1024); // 8 MB
    unsigned short* Erb = (unsigned short*)(ws + (size_t)24 * 1024 * 1024); // 256 KB

    proj_kernel<<<dim3(32, 24), dim3(256), 0, stream>>>(x, Wq, Wk, Wv, Qb, Kb, Vt);
    cvt_er<<<dim3(512), dim3(256), 0, stream>>>(Er, Erb, 2048 * 64);
    attn_kernel<<<dim3(32, 32), dim3(256), 0, stream>>>(Qb, Kb, Vt, Erb, out);
}

// Round 4
// 376.334 us; speedup vs baseline: 1.9889x; 1.9889x over previous
//
#include <hip/hip_runtime.h>
#include <hip/hip_bf16.h>
#include <stdint.h>

// Problem constants
#define S_LEN 2048
#define EMB   1024
#define NH    16
#define DH    64
#define BATCH 2

typedef short bf16x8 __attribute__((ext_vector_type(8)));
typedef float f32x4  __attribute__((ext_vector_type(4)));

__device__ __forceinline__ unsigned short f2bf(float f) {
    union { float f; unsigned int u; } v; v.f = f;
    unsigned int r = v.u + 0x7FFFu + ((v.u >> 16) & 1u);
    return (unsigned short)(r >> 16);
}

__device__ __forceinline__ bf16x8 load8f_to_bf(const float* __restrict__ p) {
    const float4* p4 = (const float4*)p;
    float4 x0 = p4[0];
    float4 x1 = p4[1];
    bf16x8 r;
    r[0] = (short)f2bf(x0.x); r[1] = (short)f2bf(x0.y);
    r[2] = (short)f2bf(x0.z); r[3] = (short)f2bf(x0.w);
    r[4] = (short)f2bf(x1.x); r[5] = (short)f2bf(x1.y);
    r[6] = (short)f2bf(x1.z); r[7] = (short)f2bf(x1.w);
    return r;
}

// ---------------------------------------------------------------------------
// Kernel 1: fused QKV projection (unchanged from round 3).
// ---------------------------------------------------------------------------
__global__ __launch_bounds__(256) void proj_kernel(
    const float* __restrict__ x,
    const float* __restrict__ Wq, const float* __restrict__ Wk,
    const float* __restrict__ Wv,
    unsigned short* __restrict__ Qb, unsigned short* __restrict__ Kb,
    unsigned short* __restrict__ Vt)
{
    const int tid  = threadIdx.x;
    const int lane = tid & 63;
    const int w    = tid >> 6;
    const int wr   = w >> 1;
    const int wc   = w & 1;
    const int m0   = blockIdx.x * 128 + wr * 64;
    const int c0   = blockIdx.y * 128 + wc * 64;
    const int wsel = c0 >> 10;
    const int f0   = c0 & 1023;
    const float* __restrict__ W = (wsel == 0) ? Wq : (wsel == 1) ? Wk : Wv;

    const int lr = lane & 15;
    const int lk = (lane >> 4) * 8;

    f32x4 acc[4][4];
#pragma unroll
    for (int i = 0; i < 4; i++)
#pragma unroll
        for (int n = 0; n < 4; n++) acc[i][n] = (f32x4){0.f, 0.f, 0.f, 0.f};

    for (int k0 = 0; k0 < 1024; k0 += 32) {
        bf16x8 a[4], b[4];
#pragma unroll
        for (int i = 0; i < 4; i++)
            a[i] = load8f_to_bf(&x[(size_t)(m0 + i * 16 + lr) * 1024 + k0 + lk]);
#pragma unroll
        for (int n = 0; n < 4; n++)
            b[n] = load8f_to_bf(&W[(size_t)(f0 + n * 16 + lr) * 1024 + k0 + lk]);
#pragma unroll
        for (int i = 0; i < 4; i++)
#pragma unroll
            for (int n = 0; n < 4; n++)
                acc[i][n] = __builtin_amdgcn_mfma_f32_16x16x32_bf16(a[i], b[n], acc[i][n], 0, 0, 0);
    }

    const int g = lane >> 4;
#pragma unroll
    for (int i = 0; i < 4; i++) {
#pragma unroll
        for (int n = 0; n < 4; n++) {
#pragma unroll
            for (int j = 0; j < 4; j++) {
                int row_m = m0 + i * 16 + g * 4 + j;
                int c     = c0 + n * 16 + lr;
                int f     = c & 1023;
                int h     = f >> 6;
                int dd    = f & 63;
                int bb    = row_m >> 11;
                int s     = row_m & 2047;
                int bh    = bb * 16 + h;
                unsigned short bv = f2bf(acc[i][n][j]);
                if (wsel == 0)      Qb[((size_t)bh * 2048 + s) * 64 + dd] = bv;
                else if (wsel == 1) Kb[((size_t)bh * 2048 + s) * 64 + dd] = bv;
                else                Vt[((size_t)bh * 64 + dd) * 2048 + s] = bv;
            }
        }
    }
}

__global__ void cvt_er(const float* __restrict__ Er, unsigned short* __restrict__ Erb, int n)
{
    int i = blockIdx.x * 256 + threadIdx.x;
    if (i < n) Erb[i] = f2bf(Er[i]);
}

// ---------------------------------------------------------------------------
// Kernel 2: flash attention with relative positions — balanced + localized.
// Grid: 512 blocks. Block i: xcd=i&7, j=i>>3, bh=(xcd<<2)|(j&3), pair=j>>2.
//  -> XCD x serves only bh in {4x..4x+3}: K/V working set 2 MB per XCD L2.
// Each block processes q-tiles {31-pair, pair}: exactly 33 iterations/block.
// 4 waves x 16-row strips; NO barriers (Rt/Pl are per-wave LDS regions,
// intra-wave DS ops are in-order at the LDS unit). K register double-buffer
// (unroll-by-2, static buffers) prefetches next tile under current compute.
// ---------------------------------------------------------------------------
__global__ __launch_bounds__(256) void attn_kernel(
    const unsigned short* __restrict__ Qb, const unsigned short* __restrict__ Kb,
    const unsigned short* __restrict__ Vt, const unsigned short* __restrict__ Erb,
    float* __restrict__ out)
{
    __shared__ __align__(16) float          Rt[4][16][84];  // pad 80->84: 2-way banks
    __shared__ __align__(16) unsigned short Pl[4][16][72];

    const int tid  = threadIdx.x;
    const int lane = tid & 63;
    const int w    = tid >> 6;

    const int i0   = blockIdx.x;
    const int xcd  = i0 & 7;
    const int jj0  = i0 >> 3;
    const int bh   = (xcd << 2) | (jj0 & 3);
    const int pair = jj0 >> 2;                 // 0..15

    const int lr = lane & 15;
    const int g  = lane >> 4;
    const int lk = g * 8;

    const unsigned short* __restrict__ Qrow = Qb + (size_t)bh * 2048 * 64;
    const unsigned short* __restrict__ Krow = Kb + (size_t)bh * 2048 * 64;
    const unsigned short* __restrict__ Vrow = Vt + (size_t)bh * 64 * 2048;

    const float SCL = 0.125f * 1.44269504089f;  // (1/sqrt(64)) * log2(e)
    const int bb = bh >> 4;
    const int h  = bh & 15;

    const int tiles[2] = {31 - pair, pair};     // heavy first; total 33 iters

#pragma unroll 1
    for (int tt = 0; tt < 2; tt++) {
        const int qt  = tiles[tt];
        const int q0w = qt * 64 + w * 16;

        // Q fragments in registers for this tile
        bf16x8 aq[2];
        aq[0] = *(const bf16x8*)&Qrow[(size_t)(q0w + lr) * 64 + 0  + lk];
        aq[1] = *(const bf16x8*)&Qrow[(size_t)(q0w + lr) * 64 + 32 + lk];

        f32x4 o[4];
#pragma unroll
        for (int n = 0; n < 4; n++) o[n] = (f32x4){0.f, 0.f, 0.f, 0.f};
        float m[4], lsum[4];
#pragma unroll
        for (int j = 0; j < 4; j++) { m[j] = -1e30f; lsum[j] = 0.f; }

        auto loadK = [&](bf16x8 (&kb)[2][4], int kt) {
            const int k0 = kt * 64;
#pragma unroll
            for (int kk = 0; kk < 2; kk++)
#pragma unroll
                for (int n = 0; n < 4; n++)
                    kb[kk][n] = *(const bf16x8*)&Krow[(size_t)(k0 + n * 16 + lr) * 64 + kk * 32 + lk];
        };

        auto body = [&](const bf16x8 (&kb)[2][4], int kt) {
            const int k0 = kt * 64;

            // ---- QK^T : 16x64 strip (K already in registers) ----
            f32x4 s[4];
#pragma unroll
            for (int n = 0; n < 4; n++) s[n] = (f32x4){0.f, 0.f, 0.f, 0.f};
#pragma unroll
            for (int kk = 0; kk < 2; kk++)
#pragma unroll
                for (int n = 0; n < 4; n++)
                    s[n] = __builtin_amdgcn_mfma_f32_16x16x32_bf16(aq[kk], kb[kk][n], s[n], 0, 0, 0);

            // ---- Q @ Er-window^T : 16x80 strip ----
            f32x4 r[5];
#pragma unroll
            for (int n = 0; n < 5; n++) r[n] = (f32x4){0.f, 0.f, 0.f, 0.f};
            const int rbase = 2047 + k0 - q0w - 15;
#pragma unroll
            for (int kk = 0; kk < 2; kk++) {
#pragma unroll
                for (int n = 0; n < 5; n++) {
                    int rr = rbase + n * 16 + lr;
                    rr = rr < 0 ? 0 : (rr > 2047 ? 2047 : rr);
                    bf16x8 be = *(const bf16x8*)&Erb[(size_t)rr * 64 + kk * 32 + lk];
                    r[n] = __builtin_amdgcn_mfma_f32_16x16x32_bf16(aq[kk], be, r[n], 0, 0, 0);
                }
            }

            // ---- V loads issued early; consumed after softmax ----
            bf16x8 vv[2][4];
#pragma unroll
            for (int kk = 0; kk < 2; kk++)
#pragma unroll
                for (int n = 0; n < 4; n++)
                    vv[kk][n] = *(const bf16x8*)&Vrow[(size_t)(n * 16 + lr) * 2048 + k0 + kk * 32 + lk];

            // ---- Rt exchange (intra-wave; DS ops in-order per wave) ----
#pragma unroll
            for (int n = 0; n < 5; n++)
#pragma unroll
                for (int j = 0; j < 4; j++)
                    Rt[w][g * 4 + j][n * 16 + lr] = r[n][j];

            // ---- combine + causal mask + online softmax ----
            float p[4][4];
            float pm[4];
#pragma unroll
            for (int j = 0; j < 4; j++) pm[j] = -1e30f;
#pragma unroll
            for (int n = 0; n < 4; n++) {
#pragma unroll
                for (int j = 0; j < 4; j++) {
                    int i  = g * 4 + j;
                    int jc = n * 16 + lr;
                    float sc = (s[n][j] + Rt[w][i][jc + 15 - i]) * SCL;
                    if (k0 + jc > q0w + i) sc = -1e30f;
                    p[n][j] = sc;
                    pm[j]   = fmaxf(pm[j], sc);
                }
            }
#pragma unroll
            for (int j = 0; j < 4; j++) {
                float v = pm[j];
                v = fmaxf(v, __shfl_xor(v, 1));
                v = fmaxf(v, __shfl_xor(v, 2));
                v = fmaxf(v, __shfl_xor(v, 4));
                v = fmaxf(v, __shfl_xor(v, 8));
                pm[j] = v;
            }
#pragma unroll
            for (int j = 0; j < 4; j++) {
                float mn   = fmaxf(m[j], pm[j]);
                float corr = exp2f(m[j] - mn);
                m[j] = mn;
                float rs = 0.f;
#pragma unroll
                for (int n = 0; n < 4; n++) {
                    float pv = exp2f(p[n][j] - mn);
                    p[n][j] = pv;
                    rs += pv;
                }
                rs += __shfl_xor(rs, 1);
                rs += __shfl_xor(rs, 2);
                rs += __shfl_xor(rs, 4);
                rs += __shfl_xor(rs, 8);
                lsum[j] = lsum[j] * corr + rs;
#pragma unroll
                for (int n = 0; n < 4; n++) o[n][j] *= corr;
            }

            // ---- P -> LDS (bf16) -> A-fragments (intra-wave) ----
#pragma unroll
            for (int n = 0; n < 4; n++)
#pragma unroll
                for (int j = 0; j < 4; j++)
                    Pl[w][g * 4 + j][n * 16 + lr] = f2bf(p[n][j]);

            // ---- P @ V ----
#pragma unroll
            for (int kk = 0; kk < 2; kk++) {
                bf16x8 pa = *(const bf16x8*)&Pl[w][lr][kk * 32 + lk];
#pragma unroll
                for (int n = 0; n < 4; n++)
                    o[n] = __builtin_amdgcn_mfma_f32_16x16x32_bf16(pa, vv[kk][n], o[n], 0, 0, 0);
            }
        };

        // K register double-buffer, unroll-by-2 ping-pong (static indices)
        bf16x8 kA[2][4], kB[2][4];
        loadK(kA, 0);
        int kt = 0;
        while (true) {
            if (kt + 1 <= qt) loadK(kB, kt + 1);
            body(kA, kt);
            kt++;
            if (kt > qt) break;
            if (kt + 1 <= qt) loadK(kA, kt + 1);
            body(kB, kt);
            kt++;
            if (kt > qt) break;
        }

        // ---- epilogue: out[b, q, h*64+dd] f32 ----
#pragma unroll
        for (int n = 0; n < 4; n++) {
#pragma unroll
            for (int j = 0; j < 4; j++) {
                int row = q0w + g * 4 + j;
                int col = h * 64 + n * 16 + lr;
                out[((size_t)bb * 2048 + row) * 1024 + col] = o[n][j] / lsum[j];
            }
        }
    }
}

// ---------------------------------------------------------------------------
extern "C" void kernel_launch(void* const* d_in, const int* in_sizes, int n_in,
                              void* d_out, int out_size, void* d_ws, size_t ws_size,
                              hipStream_t stream)
{
    const float* x  = (const float*)d_in[0];
    const float* Wq = (const float*)d_in[1];
    const float* Wk = (const float*)d_in[2];
    const float* Wv = (const float*)d_in[3];
    const float* Er = (const float*)d_in[4];
    float* out = (float*)d_out;   // f32 output (reference returns jnp.float32)

    char* ws = (char*)d_ws;
    unsigned short* Qb  = (unsigned short*)(ws);                            // 8 MB
    unsigned short* Kb  = (unsigned short*)(ws + (size_t)8  * 1024 * 1024); // 8 MB
    unsigned short* Vt  = (unsigned short*)(ws + (size_t)16 * 1024 * 1024); // 8 MB
    unsigned short* Erb = (unsigned short*)(ws + (size_t)24 * 1024 * 1024); // 256 KB

    proj_kernel<<<dim3(32, 24), dim3(256), 0, stream>>>(x, Wq, Wk, Wv, Qb, Kb, Vt);
    cvt_er<<<dim3(512), dim3(256), 0, stream>>>(Er, Erb, 2048 * 64);
    attn_kernel<<<dim3(512), dim3(256), 0, stream>>>(Qb, Kb, Vt, Erb, out);
}

// Round 5
// 312.063 us; speedup vs baseline: 2.3985x; 1.2060x over previous
//
#include <hip/hip_runtime.h>
#include <hip/hip_bf16.h>
#include <stdint.h>

// Problem constants
#define S_LEN 2048
#define EMB   1024
#define NH    16
#define DH    64
#define BATCH 2

typedef short bf16x8 __attribute__((ext_vector_type(8)));
typedef float f32x4  __attribute__((ext_vector_type(4)));

__device__ __forceinline__ unsigned short f2bf(float f) {
    union { float f; unsigned int u; } v; v.f = f;
    unsigned int r = v.u + 0x7FFFu + ((v.u >> 16) & 1u);
    return (unsigned short)(r >> 16);
}

__device__ __forceinline__ bf16x8 load8f_to_bf(const float* __restrict__ p) {
    const float4* p4 = (const float4*)p;
    float4 x0 = p4[0];
    float4 x1 = p4[1];
    bf16x8 r;
    r[0] = (short)f2bf(x0.x); r[1] = (short)f2bf(x0.y);
    r[2] = (short)f2bf(x0.z); r[3] = (short)f2bf(x0.w);
    r[4] = (short)f2bf(x1.x); r[5] = (short)f2bf(x1.y);
    r[6] = (short)f2bf(x1.z); r[7] = (short)f2bf(x1.w);
    return r;
}

// ---------------------------------------------------------------------------
// Kernel 0: vectorized f32 -> bf16 conversion of x, Wq, Wk, Wv, Er.
// Moves the per-element convert cost OUT of proj's hot loop (was ~190 VALU
// ops per 16-MFMA k-step). One pass, 8 elems/thread/iter.
// ---------------------------------------------------------------------------
__global__ __launch_bounds__(256) void cvt_bf16(
    const float* __restrict__ x,  const float* __restrict__ wq,
    const float* __restrict__ wk, const float* __restrict__ wv,
    const float* __restrict__ er,
    unsigned short* __restrict__ xb, unsigned short* __restrict__ wb,
    unsigned short* __restrict__ erb)
{
    const int NX = 4194304 / 8, NW = 1048576 / 8, NE = 131072 / 8;
    const int total = NX + 3 * NW + NE;
    for (int i8 = blockIdx.x * 256 + threadIdx.x; i8 < total; i8 += gridDim.x * 256) {
        const float* src; unsigned short* dst; int off;
        if      (i8 < NX)          { src = x;  dst = xb;            off = i8; }
        else if (i8 < NX + NW)     { src = wq; dst = wb;            off = i8 - NX; }
        else if (i8 < NX + 2 * NW) { src = wk; dst = wb + 1048576;  off = i8 - NX - NW; }
        else if (i8 < NX + 3 * NW) { src = wv; dst = wb + 2097152;  off = i8 - NX - 2 * NW; }
        else                       { src = er; dst = erb;           off = i8 - NX - 3 * NW; }
        ((bf16x8*)dst)[off] = load8f_to_bf(src + (size_t)off * 8);
    }
}

// ---------------------------------------------------------------------------
// Kernel 1 (fast path): QKV projection from PRE-CONVERTED bf16 inputs.
// Hot loop: 8 x 16B loads + 16 MFMA, no converts.
// ---------------------------------------------------------------------------
__global__ __launch_bounds__(256) void proj_kernel_bf(
    const unsigned short* __restrict__ xb, const unsigned short* __restrict__ wb,
    unsigned short* __restrict__ Qb, unsigned short* __restrict__ Kb,
    unsigned short* __restrict__ Vt)
{
    const int tid  = threadIdx.x;
    const int lane = tid & 63;
    const int w    = tid >> 6;
    const int wr   = w >> 1;
    const int wc   = w & 1;
    const int m0   = blockIdx.x * 128 + wr * 64;
    const int c0   = blockIdx.y * 128 + wc * 64;
    const int wsel = c0 >> 10;
    const int f0   = c0 & 1023;
    const unsigned short* __restrict__ W = wb + (size_t)wsel * 1048576;

    const int lr = lane & 15;
    const int lk = (lane >> 4) * 8;

    f32x4 acc[4][4];
#pragma unroll
    for (int i = 0; i < 4; i++)
#pragma unroll
        for (int n = 0; n < 4; n++) acc[i][n] = (f32x4){0.f, 0.f, 0.f, 0.f};

    for (int k0 = 0; k0 < 1024; k0 += 32) {
        bf16x8 a[4], b[4];
#pragma unroll
        for (int i = 0; i < 4; i++)
            a[i] = *(const bf16x8*)&xb[(size_t)(m0 + i * 16 + lr) * 1024 + k0 + lk];
#pragma unroll
        for (int n = 0; n < 4; n++)
            b[n] = *(const bf16x8*)&W[(size_t)(f0 + n * 16 + lr) * 1024 + k0 + lk];
#pragma unroll
        for (int i = 0; i < 4; i++)
#pragma unroll
            for (int n = 0; n < 4; n++)
                acc[i][n] = __builtin_amdgcn_mfma_f32_16x16x32_bf16(a[i], b[n], acc[i][n], 0, 0, 0);
    }

    const int g = lane >> 4;
#pragma unroll
    for (int i = 0; i < 4; i++) {
#pragma unroll
        for (int n = 0; n < 4; n++) {
#pragma unroll
            for (int j = 0; j < 4; j++) {
                int row_m = m0 + i * 16 + g * 4 + j;
                int c     = c0 + n * 16 + lr;
                int f     = c & 1023;
                int h     = f >> 6;
                int dd    = f & 63;
                int bb    = row_m >> 11;
                int s     = row_m & 2047;
                int bh    = bb * 16 + h;
                unsigned short bv = f2bf(acc[i][n][j]);
                if (wsel == 0)      Qb[((size_t)bh * 2048 + s) * 64 + dd] = bv;
                else if (wsel == 1) Kb[((size_t)bh * 2048 + s) * 64 + dd] = bv;
                else                Vt[((size_t)bh * 64 + dd) * 2048 + s] = bv;
            }
        }
    }
}

// ---------------------------------------------------------------------------
// Kernel 1 (fallback, r4 version): QKV projection from f32 with in-loop cvt.
// Used only if ws_size can't hold the bf16 copies.
// ---------------------------------------------------------------------------
__global__ __launch_bounds__(256) void proj_kernel_f32(
    const float* __restrict__ x,
    const float* __restrict__ Wq, const float* __restrict__ Wk,
    const float* __restrict__ Wv,
    unsigned short* __restrict__ Qb, unsigned short* __restrict__ Kb,
    unsigned short* __restrict__ Vt)
{
    const int tid  = threadIdx.x;
    const int lane = tid & 63;
    const int w    = tid >> 6;
    const int wr   = w >> 1;
    const int wc   = w & 1;
    const int m0   = blockIdx.x * 128 + wr * 64;
    const int c0   = blockIdx.y * 128 + wc * 64;
    const int wsel = c0 >> 10;
    const int f0   = c0 & 1023;
    const float* __restrict__ W = (wsel == 0) ? Wq : (wsel == 1) ? Wk : Wv;

    const int lr = lane & 15;
    const int lk = (lane >> 4) * 8;

    f32x4 acc[4][4];
#pragma unroll
    for (int i = 0; i < 4; i++)
#pragma unroll
        for (int n = 0; n < 4; n++) acc[i][n] = (f32x4){0.f, 0.f, 0.f, 0.f};

    for (int k0 = 0; k0 < 1024; k0 += 32) {
        bf16x8 a[4], b[4];
#pragma unroll
        for (int i = 0; i < 4; i++)
            a[i] = load8f_to_bf(&x[(size_t)(m0 + i * 16 + lr) * 1024 + k0 + lk]);
#pragma unroll
        for (int n = 0; n < 4; n++)
            b[n] = load8f_to_bf(&W[(size_t)(f0 + n * 16 + lr) * 1024 + k0 + lk]);
#pragma unroll
        for (int i = 0; i < 4; i++)
#pragma unroll
            for (int n = 0; n < 4; n++)
                acc[i][n] = __builtin_amdgcn_mfma_f32_16x16x32_bf16(a[i], b[n], acc[i][n], 0, 0, 0);
    }

    const int g = lane >> 4;
#pragma unroll
    for (int i = 0; i < 4; i++) {
#pragma unroll
        for (int n = 0; n < 4; n++) {
#pragma unroll
            for (int j = 0; j < 4; j++) {
                int row_m = m0 + i * 16 + g * 4 + j;
                int c     = c0 + n * 16 + lr;
                int f     = c & 1023;
                int h     = f >> 6;
                int dd    = f & 63;
                int bb    = row_m >> 11;
                int s     = row_m & 2047;
                int bh    = bb * 16 + h;
                unsigned short bv = f2bf(acc[i][n][j]);
                if (wsel == 0)      Qb[((size_t)bh * 2048 + s) * 64 + dd] = bv;
                else if (wsel == 1) Kb[((size_t)bh * 2048 + s) * 64 + dd] = bv;
                else                Vt[((size_t)bh * 64 + dd) * 2048 + s] = bv;
            }
        }
    }
}

__global__ void cvt_er(const float* __restrict__ Er, unsigned short* __restrict__ Erb, int n)
{
    int i = blockIdx.x * 256 + threadIdx.x;
    if (i < n) Erb[i] = f2bf(Er[i]);
}

// ---------------------------------------------------------------------------
// Kernel 2: flash attention with relative positions — SINGLE-WAVE blocks.
// r4's waves were fully independent (per-wave LDS, no barriers) but packaged
// 4-to-a-block; only ~1 block/CU was resident (Occupancy 11.4%). Split into
// 64-thread blocks: grid 2048, 7.7 KB LDS each -> 8 blocks/CU (VGPR-capped
// at 2 waves/SIMD), doubling resident waves.
// Mapping: i0=blockIdx.x; xcd=i0&7 serves bh in {4*xcd..4*xcd+3} (L2 pin,
// 2 MB K/V per XCD). j=i0>>3: b2=j&3, strip=(j>>2)&3, pair=j>>4.
// Each block: q-tiles {31-pair, pair} x one 16-row strip = 33 kt-iterations.
// ---------------------------------------------------------------------------
__global__ __launch_bounds__(64) void attn_kernel(
    const unsigned short* __restrict__ Qb, const unsigned short* __restrict__ Kb,
    const unsigned short* __restrict__ Vt, const unsigned short* __restrict__ Erb,
    float* __restrict__ out)
{
    __shared__ __align__(16) float          Rt[16][84];  // pad 80->84
    __shared__ __align__(16) unsigned short Pl[16][72];

    const int lane = threadIdx.x & 63;

    const int i0    = blockIdx.x;
    const int xcd   = i0 & 7;
    const int j0    = i0 >> 3;
    const int b2    = j0 & 3;
    const int strip = (j0 >> 2) & 3;
    const int pair  = j0 >> 4;                 // 0..15
    const int bh    = (xcd << 2) | b2;

    const int lr = lane & 15;
    const int g  = lane >> 4;
    const int lk = g * 8;

    const unsigned short* __restrict__ Qrow = Qb + (size_t)bh * 2048 * 64;
    const unsigned short* __restrict__ Krow = Kb + (size_t)bh * 2048 * 64;
    const unsigned short* __restrict__ Vrow = Vt + (size_t)bh * 64 * 2048;

    const float SCL = 0.125f * 1.44269504089f;  // (1/sqrt(64)) * log2(e)
    const int bb = bh >> 4;
    const int h  = bh & 15;

#pragma unroll 1
    for (int tt = 0; tt < 2; tt++) {
        const int qt  = tt ? pair : 31 - pair;  // heavy first; 33 iters total
        const int q0w = qt * 64 + strip * 16;

        bf16x8 aq[2];
        aq[0] = *(const bf16x8*)&Qrow[(size_t)(q0w + lr) * 64 + 0  + lk];
        aq[1] = *(const bf16x8*)&Qrow[(size_t)(q0w + lr) * 64 + 32 + lk];

        f32x4 o[4];
#pragma unroll
        for (int n = 0; n < 4; n++) o[n] = (f32x4){0.f, 0.f, 0.f, 0.f};
        float m[4], lsum[4];
#pragma unroll
        for (int j = 0; j < 4; j++) { m[j] = -1e30f; lsum[j] = 0.f; }

        auto loadK = [&](bf16x8 (&kb)[2][4], int kt) {
            const int k0 = kt * 64;
#pragma unroll
            for (int kk = 0; kk < 2; kk++)
#pragma unroll
                for (int n = 0; n < 4; n++)
                    kb[kk][n] = *(const bf16x8*)&Krow[(size_t)(k0 + n * 16 + lr) * 64 + kk * 32 + lk];
        };

        auto body = [&](const bf16x8 (&kb)[2][4], int kt) {
            const int k0 = kt * 64;

            // ---- QK^T (K in registers) ----
            f32x4 s[4];
#pragma unroll
            for (int n = 0; n < 4; n++) s[n] = (f32x4){0.f, 0.f, 0.f, 0.f};
#pragma unroll
            for (int kk = 0; kk < 2; kk++)
#pragma unroll
                for (int n = 0; n < 4; n++)
                    s[n] = __builtin_amdgcn_mfma_f32_16x16x32_bf16(aq[kk], kb[kk][n], s[n], 0, 0, 0);

            // ---- Q @ Er-window^T : 16x80 ----
            f32x4 r[5];
#pragma unroll
            for (int n = 0; n < 5; n++) r[n] = (f32x4){0.f, 0.f, 0.f, 0.f};
            const int rbase = 2047 + k0 - q0w - 15;
#pragma unroll
            for (int kk = 0; kk < 2; kk++) {
#pragma unroll
                for (int n = 0; n < 5; n++) {
                    int rr = rbase + n * 16 + lr;
                    rr = rr < 0 ? 0 : (rr > 2047 ? 2047 : rr);
                    bf16x8 be = *(const bf16x8*)&Erb[(size_t)rr * 64 + kk * 32 + lk];
                    r[n] = __builtin_amdgcn_mfma_f32_16x16x32_bf16(aq[kk], be, r[n], 0, 0, 0);
                }
            }

            // ---- V loads issued early ----
            bf16x8 vv[2][4];
#pragma unroll
            for (int kk = 0; kk < 2; kk++)
#pragma unroll
                for (int n = 0; n < 4; n++)
                    vv[kk][n] = *(const bf16x8*)&Vrow[(size_t)(n * 16 + lr) * 2048 + k0 + kk * 32 + lk];

            // ---- Rt exchange (intra-wave; DS ops in-order per wave) ----
#pragma unroll
            for (int n = 0; n < 5; n++)
#pragma unroll
                for (int j = 0; j < 4; j++)
                    Rt[g * 4 + j][n * 16 + lr] = r[n][j];

            // ---- combine + causal mask + online softmax ----
            float p[4][4];
            float pm[4];
#pragma unroll
            for (int j = 0; j < 4; j++) pm[j] = -1e30f;
#pragma unroll
            for (int n = 0; n < 4; n++) {
#pragma unroll
                for (int j = 0; j < 4; j++) {
                    int i  = g * 4 + j;
                    int jc = n * 16 + lr;
                    float sc = (s[n][j] + Rt[i][jc + 15 - i]) * SCL;
                    if (k0 + jc > q0w + i) sc = -1e30f;
                    p[n][j] = sc;
                    pm[j]   = fmaxf(pm[j], sc);
                }
            }
#pragma unroll
            for (int j = 0; j < 4; j++) {
                float v = pm[j];
                v = fmaxf(v, __shfl_xor(v, 1));
                v = fmaxf(v, __shfl_xor(v, 2));
                v = fmaxf(v, __shfl_xor(v, 4));
                v = fmaxf(v, __shfl_xor(v, 8));
                pm[j] = v;
            }
#pragma unroll
            for (int j = 0; j < 4; j++) {
                float mn   = fmaxf(m[j], pm[j]);
                float corr = exp2f(m[j] - mn);
                m[j] = mn;
                float rs = 0.f;
#pragma unroll
                for (int n = 0; n < 4; n++) {
                    float pv = exp2f(p[n][j] - mn);
                    p[n][j] = pv;
                    rs += pv;
                }
                rs += __shfl_xor(rs, 1);
                rs += __shfl_xor(rs, 2);
                rs += __shfl_xor(rs, 4);
                rs += __shfl_xor(rs, 8);
                lsum[j] = lsum[j] * corr + rs;
#pragma unroll
                for (int n = 0; n < 4; n++) o[n][j] *= corr;
            }

            // ---- P -> LDS (bf16) -> A-fragments ----
#pragma unroll
            for (int n = 0; n < 4; n++)
#pragma unroll
                for (int j = 0; j < 4; j++)
                    Pl[g * 4 + j][n * 16 + lr] = f2bf(p[n][j]);

            // ---- P @ V ----
#pragma unroll
            for (int kk = 0; kk < 2; kk++) {
                bf16x8 pa = *(const bf16x8*)&Pl[lr][kk * 32 + lk];
#pragma unroll
                for (int n = 0; n < 4; n++)
                    o[n] = __builtin_amdgcn_mfma_f32_16x16x32_bf16(pa, vv[kk][n], o[n], 0, 0, 0);
            }
        };

        // K register double-buffer, ping-pong with static buffers
        bf16x8 kA[2][4], kB[2][4];
        loadK(kA, 0);
        int kt = 0;
        while (true) {
            if (kt + 1 <= qt) loadK(kB, kt + 1);
            body(kA, kt);
            kt++;
            if (kt > qt) break;
            if (kt + 1 <= qt) loadK(kA, kt + 1);
            body(kB, kt);
            kt++;
            if (kt > qt) break;
        }

        // ---- epilogue: out[b, q, h*64+dd] f32 ----
#pragma unroll
        for (int n = 0; n < 4; n++) {
#pragma unroll
            for (int j = 0; j < 4; j++) {
                int row = q0w + g * 4 + j;
                int col = h * 64 + n * 16 + lr;
                out[((size_t)bb * 2048 + row) * 1024 + col] = o[n][j] / lsum[j];
            }
        }
    }
}

// ---------------------------------------------------------------------------
extern "C" void kernel_launch(void* const* d_in, const int* in_sizes, int n_in,
                              void* d_out, int out_size, void* d_ws, size_t ws_size,
                              hipStream_t stream)
{
    const float* x  = (const float*)d_in[0];
    const float* Wq = (const float*)d_in[1];
    const float* Wk = (const float*)d_in[2];
    const float* Wv = (const float*)d_in[3];
    const float* Er = (const float*)d_in[4];
    float* out = (float*)d_out;   // f32 output (reference returns jnp.float32)

    char* ws = (char*)d_ws;
    const size_t MB = 1024 * 1024;
    unsigned short* Qb  = (unsigned short*)(ws);            // 8 MB
    unsigned short* Kb  = (unsigned short*)(ws + 8  * MB);  // 8 MB
    unsigned short* Vt  = (unsigned short*)(ws + 16 * MB);  // 8 MB
    unsigned short* Erb = (unsigned short*)(ws + 24 * MB);  // 256 KB
    unsigned short* xb  = (unsigned short*)(ws + 25 * MB);  // 8 MB
    unsigned short* wb  = (unsigned short*)(ws + 33 * MB);  // 6 MB  (total 39 MB)

    if (ws_size >= (size_t)39 * MB) {
        cvt_bf16<<<dim3(1024), dim3(256), 0, stream>>>(x, Wq, Wk, Wv, Er, xb, wb, Erb);
        proj_kernel_bf<<<dim3(32, 24), dim3(256), 0, stream>>>(xb, wb, Qb, Kb, Vt);
    } else {
        cvt_er<<<dim3(512), dim3(256), 0, stream>>>(Er, Erb, 2048 * 64);
        proj_kernel_f32<<<dim3(32, 24), dim3(256), 0, stream>>>(x, Wq, Wk, Wv, Qb, Kb, Vt);
    }
    attn_kernel<<<dim3(2048), dim3(64), 0, stream>>>(Qb, Kb, Vt, Erb, out);
}

// Round 7
// 308.618 us; speedup vs baseline: 2.4253x; 1.0112x over previous
//
#include <hip/hip_runtime.h>
#include <hip/hip_bf16.h>
#include <stdint.h>

// Problem constants
#define S_LEN 2048
#define EMB   1024
#define NH    16
#define DH    64
#define BATCH 2

typedef short bf16x8 __attribute__((ext_vector_type(8)));
typedef float f32x4  __attribute__((ext_vector_type(4)));

__device__ __forceinline__ unsigned short f2bf(float f) {
    union { float f; unsigned int u; } v; v.f = f;
    unsigned int r = v.u + 0x7FFFu + ((v.u >> 16) & 1u);
    return (unsigned short)(r >> 16);
}

__device__ __forceinline__ bf16x8 load8f_to_bf(const float* __restrict__ p) {
    const float4* p4 = (const float4*)p;
    float4 x0 = p4[0];
    float4 x1 = p4[1];
    bf16x8 r;
    r[0] = (short)f2bf(x0.x); r[1] = (short)f2bf(x0.y);
    r[2] = (short)f2bf(x0.z); r[3] = (short)f2bf(x0.w);
    r[4] = (short)f2bf(x1.x); r[5] = (short)f2bf(x1.y);
    r[6] = (short)f2bf(x1.z); r[7] = (short)f2bf(x1.w);
    return r;
}

// ---------------------------------------------------------------------------
// Kernel 0: vectorized f32 -> bf16 conversion of x, Wq, Wk, Wv, Er.
// ---------------------------------------------------------------------------
__global__ __launch_bounds__(256) void cvt_bf16(
    const float* __restrict__ x,  const float* __restrict__ wq,
    const float* __restrict__ wk, const float* __restrict__ wv,
    const float* __restrict__ er,
    unsigned short* __restrict__ xb, unsigned short* __restrict__ wb,
    unsigned short* __restrict__ erb)
{
    const int NX = 4194304 / 8, NW = 1048576 / 8, NE = 131072 / 8;
    const int total = NX + 3 * NW + NE;
    for (int i8 = blockIdx.x * 256 + threadIdx.x; i8 < total; i8 += gridDim.x * 256) {
        const float* src; unsigned short* dst; int off;
        if      (i8 < NX)          { src = x;  dst = xb;            off = i8; }
        else if (i8 < NX + NW)     { src = wq; dst = wb;            off = i8 - NX; }
        else if (i8 < NX + 2 * NW) { src = wk; dst = wb + 1048576;  off = i8 - NX - NW; }
        else if (i8 < NX + 3 * NW) { src = wv; dst = wb + 2097152;  off = i8 - NX - 2 * NW; }
        else                       { src = er; dst = erb;           off = i8 - NX - 3 * NW; }
        ((bf16x8*)dst)[off] = load8f_to_bf(src + (size_t)off * 8);
    }
}

// ---------------------------------------------------------------------------
// Kernel 1 (fast path): QKV projection from pre-converted bf16 inputs.
// ---------------------------------------------------------------------------
__global__ __launch_bounds__(256) void proj_kernel_bf(
    const unsigned short* __restrict__ xb, const unsigned short* __restrict__ wb,
    unsigned short* __restrict__ Qb, unsigned short* __restrict__ Kb,
    unsigned short* __restrict__ Vt)
{
    const int tid  = threadIdx.x;
    const int lane = tid & 63;
    const int w    = tid >> 6;
    const int wr   = w >> 1;
    const int wc   = w & 1;
    const int m0   = blockIdx.x * 128 + wr * 64;
    const int c0   = blockIdx.y * 128 + wc * 64;
    const int wsel = c0 >> 10;
    const int f0   = c0 & 1023;
    const unsigned short* __restrict__ W = wb + (size_t)wsel * 1048576;

    const int lr = lane & 15;
    const int lk = (lane >> 4) * 8;

    f32x4 acc[4][4];
#pragma unroll
    for (int i = 0; i < 4; i++)
#pragma unroll
        for (int n = 0; n < 4; n++) acc[i][n] = (f32x4){0.f, 0.f, 0.f, 0.f};

    for (int k0 = 0; k0 < 1024; k0 += 32) {
        bf16x8 a[4], b[4];
#pragma unroll
        for (int i = 0; i < 4; i++)
            a[i] = *(const bf16x8*)&xb[(size_t)(m0 + i * 16 + lr) * 1024 + k0 + lk];
#pragma unroll
        for (int n = 0; n < 4; n++)
            b[n] = *(const bf16x8*)&W[(size_t)(f0 + n * 16 + lr) * 1024 + k0 + lk];
#pragma unroll
        for (int i = 0; i < 4; i++)
#pragma unroll
            for (int n = 0; n < 4; n++)
                acc[i][n] = __builtin_amdgcn_mfma_f32_16x16x32_bf16(a[i], b[n], acc[i][n], 0, 0, 0);
    }

    const int g = lane >> 4;
#pragma unroll
    for (int i = 0; i < 4; i++) {
#pragma unroll
        for (int n = 0; n < 4; n++) {
#pragma unroll
            for (int j = 0; j < 4; j++) {
                int row_m = m0 + i * 16 + g * 4 + j;
                int c     = c0 + n * 16 + lr;
                int f     = c & 1023;
                int h     = f >> 6;
                int dd    = f & 63;
                int bb    = row_m >> 11;
                int s     = row_m & 2047;
                int bh    = bb * 16 + h;
                unsigned short bv = f2bf(acc[i][n][j]);
                if (wsel == 0)      Qb[((size_t)bh * 2048 + s) * 64 + dd] = bv;
                else if (wsel == 1) Kb[((size_t)bh * 2048 + s) * 64 + dd] = bv;
                else                Vt[((size_t)bh * 64 + dd) * 2048 + s] = bv;
            }
        }
    }
}

// ---------------------------------------------------------------------------
// Kernel 1 (fallback): f32 inputs with in-loop convert.
// ---------------------------------------------------------------------------
__global__ __launch_bounds__(256) void proj_kernel_f32(
    const float* __restrict__ x,
    const float* __restrict__ Wq, const float* __restrict__ Wk,
    const float* __restrict__ Wv,
    unsigned short* __restrict__ Qb, unsigned short* __restrict__ Kb,
    unsigned short* __restrict__ Vt)
{
    const int tid  = threadIdx.x;
    const int lane = tid & 63;
    const int w    = tid >> 6;
    const int wr   = w >> 1;
    const int wc   = w & 1;
    const int m0   = blockIdx.x * 128 + wr * 64;
    const int c0   = blockIdx.y * 128 + wc * 64;
    const int wsel = c0 >> 10;
    const int f0   = c0 & 1023;
    const float* __restrict__ W = (wsel == 0) ? Wq : (wsel == 1) ? Wk : Wv;

    const int lr = lane & 15;
    const int lk = (lane >> 4) * 8;

    f32x4 acc[4][4];
#pragma unroll
    for (int i = 0; i < 4; i++)
#pragma unroll
        for (int n = 0; n < 4; n++) acc[i][n] = (f32x4){0.f, 0.f, 0.f, 0.f};

    for (int k0 = 0; k0 < 1024; k0 += 32) {
        bf16x8 a[4], b[4];
#pragma unroll
        for (int i = 0; i < 4; i++)
            a[i] = load8f_to_bf(&x[(size_t)(m0 + i * 16 + lr) * 1024 + k0 + lk]);
#pragma unroll
        for (int n = 0; n < 4; n++)
            b[n] = load8f_to_bf(&W[(size_t)(f0 + n * 16 + lr) * 1024 + k0 + lk]);
#pragma unroll
        for (int i = 0; i < 4; i++)
#pragma unroll
            for (int n = 0; n < 4; n++)
                acc[i][n] = __builtin_amdgcn_mfma_f32_16x16x32_bf16(a[i], b[n], acc[i][n], 0, 0, 0);
    }

    const int g = lane >> 4;
#pragma unroll
    for (int i = 0; i < 4; i++) {
#pragma unroll
        for (int n = 0; n < 4; n++) {
#pragma unroll
            for (int j = 0; j < 4; j++) {
                int row_m = m0 + i * 16 + g * 4 + j;
                int c     = c0 + n * 16 + lr;
                int f     = c & 1023;
                int h     = f >> 6;
                int dd    = f & 63;
                int bb    = row_m >> 11;
                int s     = row_m & 2047;
                int bh    = bb * 16 + h;
                unsigned short bv = f2bf(acc[i][n][j]);
                if (wsel == 0)      Qb[((size_t)bh * 2048 + s) * 64 + dd] = bv;
                else if (wsel == 1) Kb[((size_t)bh * 2048 + s) * 64 + dd] = bv;
                else                Vt[((size_t)bh * 64 + dd) * 2048 + s] = bv;
            }
        }
    }
}

__global__ void cvt_er(const float* __restrict__ Er, unsigned short* __restrict__ Erb, int n)
{
    int i = blockIdx.x * 256 + threadIdx.x;
    if (i < n) Erb[i] = f2bf(Er[i]);
}

// ---------------------------------------------------------------------------
// Kernel 2: flash attention, SWAPPED-OPERAND orientation (r6) + LDS FENCES.
// The Rt2/Pl exchanges are cross-lane but per-thread-address-disjoint, so the
// compiler may legally reorder ds_read above ds_write (per-thread memory
// model). __syncthreads() (1-wave block: s_waitcnt lgkmcnt(0)+s_barrier, ~free)
// pins the order. Fence placement also covers WAR across iterations.
// ---------------------------------------------------------------------------
__global__ __launch_bounds__(64, 2) void attn_kernel(
    const unsigned short* __restrict__ Qb, const unsigned short* __restrict__ Kb,
    const unsigned short* __restrict__ Vt, const unsigned short* __restrict__ Erb,
    float* __restrict__ out)
{
    __shared__ __align__(16) float          Rt2[80][18];
    __shared__ __align__(16) unsigned short Pl[16][72];

    const int lane = threadIdx.x & 63;

    const int i0    = blockIdx.x;
    const int xcd   = i0 & 7;            // XCD pin: bh in {4*xcd..4*xcd+3}
    const int j0    = i0 >> 3;
    const int b2    = j0 & 3;
    const int strip = (j0 >> 2) & 3;
    const int pair  = j0 >> 4;           // 0..15
    const int bh    = (xcd << 2) | b2;

    const int lr = lane & 15;
    const int g  = lane >> 4;
    const int lk = g * 8;

    const unsigned short* __restrict__ Qrow = Qb + (size_t)bh * 2048 * 64;
    const unsigned short* __restrict__ Krow = Kb + (size_t)bh * 2048 * 64;
    const unsigned short* __restrict__ Vrow = Vt + (size_t)bh * 64 * 2048;

    const float SCL = 0.125f * 1.44269504089f;  // (1/sqrt(64)) * log2(e)
    const int bb = bh >> 4;
    const int h  = bh & 15;

#pragma unroll 1
    for (int tt = 0; tt < 2; tt++) {
        const int qt  = tt ? pair : 31 - pair;  // heavy first; 33 iters total
        const int q0w = qt * 64 + strip * 16;

        bf16x8 aq[2];
        aq[0] = *(const bf16x8*)&Qrow[(size_t)(q0w + lr) * 64 + 0  + lk];
        aq[1] = *(const bf16x8*)&Qrow[(size_t)(q0w + lr) * 64 + 32 + lk];

        f32x4 o[4];
#pragma unroll
        for (int n = 0; n < 4; n++) o[n] = (f32x4){0.f, 0.f, 0.f, 0.f};
        float mrow = -1e30f, lsum = 0.f;

        auto loadK = [&](bf16x8 (&kb)[2][4], int kt) {
            const int k0 = kt * 64;
#pragma unroll
            for (int kk = 0; kk < 2; kk++)
#pragma unroll
                for (int n = 0; n < 4; n++)
                    kb[kk][n] = *(const bf16x8*)&Krow[(size_t)(k0 + n * 16 + lr) * 64 + kk * 32 + lk];
        };

        auto body = [&](const bf16x8 (&kb)[2][4], int kt) {
            const int k0 = kt * 64;
            const int rbase = 2047 + k0 - q0w - 15;   // >= 0 always

            // ---- S^T = K·Q^T and R^T = Er·Q^T ----
            f32x4 s[4], r[5];
#pragma unroll
            for (int n = 0; n < 4; n++) s[n] = (f32x4){0.f, 0.f, 0.f, 0.f};
#pragma unroll
            for (int n = 0; n < 5; n++) r[n] = (f32x4){0.f, 0.f, 0.f, 0.f};
#pragma unroll
            for (int kk = 0; kk < 2; kk++) {
                bf16x8 be[5];
#pragma unroll
                for (int n = 0; n < 5; n++) {
                    int rr = rbase + n * 16 + lr;
                    rr = rr > 2047 ? 2047 : rr;
                    be[n] = *(const bf16x8*)&Erb[(size_t)rr * 64 + kk * 32 + lk];
                }
#pragma unroll
                for (int n = 0; n < 4; n++)
                    s[n] = __builtin_amdgcn_mfma_f32_16x16x32_bf16(kb[kk][n], aq[kk], s[n], 0, 0, 0);
#pragma unroll
                for (int n = 0; n < 5; n++)
                    r[n] = __builtin_amdgcn_mfma_f32_16x16x32_bf16(be[n], aq[kk], r[n], 0, 0, 0);
            }

            // ---- V loads issued early (hide under LDS/softmax) ----
            bf16x8 vv[2][4];
#pragma unroll
            for (int kk = 0; kk < 2; kk++)
#pragma unroll
                for (int n = 0; n < 4; n++)
                    vv[kk][n] = *(const bf16x8*)&Vrow[(size_t)(n * 16 + lr) * 2048 + k0 + kk * 32 + lk];

            // ---- stash QEr window: same-column shift, no transpose ----
#pragma unroll
            for (int n = 0; n < 5; n++)
#pragma unroll
                for (int j = 0; j < 4; j++)
                    Rt2[n * 16 + g * 4 + j][lr] = r[n][j];

            __syncthreads();   // FENCE: Rt2 writes -> cross-lane reads

            // ---- combine + mask (in-lane) ----
            float pmax = -1e30f;
#pragma unroll
            for (int n = 0; n < 4; n++) {
#pragma unroll
                for (int j = 0; j < 4; j++) {
                    int w  = n * 16 + g * 4 + j + 15 - lr;     // window pos
                    float sc = (s[n][j] + Rt2[w][lr]) * SCL;
                    if (k0 + n * 16 + g * 4 + j > q0w + lr) sc = -1e30f;
                    s[n][j] = sc;
                    pmax = fmaxf(pmax, sc);
                }
            }
            pmax = fmaxf(pmax, __shfl_xor(pmax, 16));
            pmax = fmaxf(pmax, __shfl_xor(pmax, 32));

            // ---- defer-rescale online softmax ----
            if (__any(pmax > mrow)) {
                float mn   = fmaxf(mrow, pmax);
                float corr = exp2f(mrow - mn);
                mrow = mn;
                lsum *= corr;
#pragma unroll
                for (int j = 0; j < 4; j++) {
                    float cj = __shfl(corr, g * 4 + j);
#pragma unroll
                    for (int n = 0; n < 4; n++) o[n][j] *= cj;
                }
            }
            float rs = 0.f;
#pragma unroll
            for (int n = 0; n < 4; n++) {
#pragma unroll
                for (int j = 0; j < 4; j++) {
                    float pv = exp2f(s[n][j] - mrow);
                    rs += pv;
                    Pl[lr][n * 16 + g * 4 + j] = f2bf(pv);
                }
            }
            rs += __shfl_xor(rs, 16);
            rs += __shfl_xor(rs, 32);
            lsum += rs;

            __syncthreads();   // FENCE: Pl writes -> cross-lane A-frag reads

            // ---- P @ V ----
#pragma unroll
            for (int kk = 0; kk < 2; kk++) {
                bf16x8 pa = *(const bf16x8*)&Pl[lr][kk * 32 + lk];
#pragma unroll
                for (int n = 0; n < 4; n++)
                    o[n] = __builtin_amdgcn_mfma_f32_16x16x32_bf16(pa, vv[kk][n], o[n], 0, 0, 0);
            }
        };

        // K register double-buffer, ping-pong with static buffers
        bf16x8 kA[2][4], kB[2][4];
        loadK(kA, 0);
        int kt = 0;
        while (true) {
            if (kt + 1 <= qt) loadK(kB, kt + 1);
            body(kA, kt);
            kt++;
            if (kt > qt) break;
            if (kt + 1 <= qt) loadK(kA, kt + 1);
            body(kB, kt);
            kt++;
            if (kt > qt) break;
        }

        // ---- epilogue: out[b, q, h*64+dd] f32 ----
        float linv = 1.0f / lsum;
#pragma unroll
        for (int j = 0; j < 4; j++) {
            float lj = __shfl(linv, g * 4 + j);
#pragma unroll
            for (int n = 0; n < 4; n++) {
                int row = q0w + g * 4 + j;
                int col = h * 64 + n * 16 + lr;
                out[((size_t)bb * 2048 + row) * 1024 + col] = o[n][j] * lj;
            }
        }
    }
}

// ---------------------------------------------------------------------------
extern "C" void kernel_launch(void* const* d_in, const int* in_sizes, int n_in,
                              void* d_out, int out_size, void* d_ws, size_t ws_size,
                              hipStream_t stream)
{
    const float* x  = (const float*)d_in[0];
    const float* Wq = (const float*)d_in[1];
    const float* Wk = (const float*)d_in[2];
    const float* Wv = (const float*)d_in[3];
    const float* Er = (const float*)d_in[4];
    float* out = (float*)d_out;   // f32 output (reference returns jnp.float32)

    char* ws = (char*)d_ws;
    const size_t MB = 1024 * 1024;
    unsigned short* Qb  = (unsigned short*)(ws);            // 8 MB
    unsigned short* Kb  = (unsigned short*)(ws + 8  * MB);  // 8 MB
    unsigned short* Vt  = (unsigned short*)(ws + 16 * MB);  // 8 MB
    unsigned short* Erb = (unsigned short*)(ws + 24 * MB);  // 256 KB
    unsigned short* xb  = (unsigned short*)(ws + 25 * MB);  // 8 MB
    unsigned short* wb  = (unsigned short*)(ws + 33 * MB);  // 6 MB  (total 39 MB)

    if (ws_size >= (size_t)39 * MB) {
        cvt_bf16<<<dim3(1024), dim3(256), 0, stream>>>(x, Wq, Wk, Wv, Er, xb, wb, Erb);
        proj_kernel_bf<<<dim3(32, 24), dim3(256), 0, stream>>>(xb, wb, Qb, Kb, Vt);
    } else {
        cvt_er<<<dim3(512), dim3(256), 0, stream>>>(Er, Erb, 2048 * 64);
        proj_kernel_f32<<<dim3(32, 24), dim3(256), 0, stream>>>(x, Wq, Wk, Wv, Qb, Kb, Vt);
    }
    attn_kernel<<<dim3(2048), dim3(64), 0, stream>>>(Qb, Kb, Vt, Erb, out);
}